// Round 1
// baseline (317.901 us; speedup 1.0000x reference)
//
#include <hip/hip_runtime.h>
#include <math.h>

#define BATCH 16
#define CH    64
#define HH    128
#define WW    128
#define PLANE (HH*WW)          // 16384
#define LROW  144              // padded row stride (8 left + 128 + 8 right)
#define HROWS 74               // staged rows per half: 5 + 64 + 5
#define OUT0  (BATCH*3*CH*PLANE)  // 50331648

// ws float layout: [0,1024) M ; [1024,2048) ps ; [2048) S ; [3072) Sw ;
// [4096) Sh ; [5120) Scol ; [6144) Srow

// ---------------- Kernel 1: per-(b,c) max of x -> M, ps; zero sum slots ----
__global__ __launch_bounds__(256) void k_max(const float* __restrict__ x,
                                             float* __restrict__ ws) {
    int bid = blockIdx.x;                    // 0..1023 = b*64+c
    const float4* xp = (const float4*)(x + (size_t)bid * PLANE);
    int tid = threadIdx.x;
    float m = -INFINITY;
#pragma unroll
    for (int i = 0; i < 16; i++) {
        float4 v = xp[i * 256 + tid];
        m = fmaxf(m, fmaxf(fmaxf(v.x, v.y), fmaxf(v.z, v.w)));
    }
#pragma unroll
    for (int off = 32; off; off >>= 1) m = fmaxf(m, __shfl_xor(m, off, 64));
    __shared__ float sm[4];
    int wid = tid >> 6, lane = tid & 63;
    if (lane == 0) sm[wid] = m;
    __syncthreads();
    if (tid == 0) {
        float mm = fmaxf(fmaxf(sm[0], sm[1]), fmaxf(sm[2], sm[3]));
        float ps = 1.0f / (1.0f + expf(-mm));
        ws[bid] = ps - 0.01f;        // M
        ws[1024 + bid] = ps;         // ps
        // zero the 5 sum slots that k_fields will atomically accumulate
        ws[2048 + bid] = 0.0f;
        ws[3072 + bid] = 0.0f;
        ws[4096 + bid] = 0.0f;
        ws[5120 + bid] = 0.0f;
        ws[6144 + bid] = 0.0f;
    }
}

// ---------------- Kernel 2: fields (unmasked) + per-plane sums ----------------
// One block = one 64-row half of one (b,c) plane. LDS 42.6 KiB -> 3 blocks/CU.
__global__ __launch_bounds__(256) void k_fields(
    const float* __restrict__ x,
    const float* __restrict__ w_bbx, const float* __restrict__ w_width,
    const float* __restrict__ w_width_sh, const float* __restrict__ w_height,
    const float* __restrict__ w_height_sh,
    float* __restrict__ ws, float* __restrict__ out) {
    __shared__ float4 xs4[HROWS * (LROW / 4)];   // 74*36 float4 = 42624 B
    __shared__ float red[4 * 5];
    float* xs = (float*)xs4;
    int bid2 = blockIdx.x;                 // (b*64+c)*2 + half
    int bc = bid2 >> 1, half = bid2 & 1;
    int r0 = half * 64;
    int b = bc >> 6, c = bc & 63;
    int tid = threadIdx.x;

    // zero the whole padded LDS strip, then fill interior (rows r0-5..r0+68)
    for (int j = tid; j < HROWS * (LROW / 4); j += 256)
        xs4[j] = make_float4(0.f, 0.f, 0.f, 0.f);
    __syncthreads();
    const float* xp = x + (size_t)bc * PLANE;
    for (int j = tid; j < HROWS * 32; j += 256) {
        int i = j >> 5, c4 = j & 31;
        int gr = r0 - 5 + i;
        if ((unsigned)gr < 128u)
            *(float4*)&xs[i * LROW + 8 + c4 * 4] = ((const float4*)xp)[gr * 32 + c4];
    }
    float wk[11], hk[11];
#pragma unroll
    for (int k = 0; k < 11; k++) {
        wk[k] = w_width[c * 11 + k];
        hk[k] = w_height[c * 11 + k];
    }
    float cb = w_bbx[c];
    float cw = 128.0f * w_width_sh[c] * cb;   // * W
    float chs = 128.0f * w_height_sh[c] * cb; // * H
    float M = ws[bc];
    __syncthreads();

    float S = 0.f, Sw = 0.f, Sh = 0.f, Scol = 0.f, Srow = 0.f;
    float* outS = out + (size_t)(b * 192 + c) * PLANE;
    float* outW = out + (size_t)(b * 192 + 64 + c) * PLANE;
    float* outH = out + (size_t)(b * 192 + 128 + c) * PLANE;
    int obase = r0 * 32;                   // float4 offset of this half

    for (int g = 0; g < 8; g++) {
        int idx = g * 256 + tid;           // float4 index in half-plane
        int p = idx * 4;
        int y = p >> 7, xc = p & 127;      // y = local row 0..63
        // vertical 11-tap conv on 4 adjacent columns (staged rows y..y+10)
        float4 vx;                          // center row (k=5) = raw x
        float hx = 0.f, hy = 0.f, hz = 0.f, hw = 0.f;
#pragma unroll
        for (int k = 0; k < 11; k++) {
            float4 v = *(const float4*)&xs[(y + k) * LROW + xc + 8];
            if (k == 5) vx = v;
            hx += v.x * hk[k]; hy += v.y * hk[k];
            hz += v.z * hk[k]; hw += v.w * hk[k];
        }
        // horizontal window: padded cols xc..xc+19 (orig xc-8 .. xc+11)
        float wbuf[20];
        {
            float4 a0 = *(const float4*)&xs[(y + 5) * LROW + xc + 0];
            float4 a1 = *(const float4*)&xs[(y + 5) * LROW + xc + 4];
            float4 a3 = *(const float4*)&xs[(y + 5) * LROW + xc + 12];
            float4 a4 = *(const float4*)&xs[(y + 5) * LROW + xc + 16];
            wbuf[0] = a0.x;  wbuf[1] = a0.y;  wbuf[2] = a0.z;  wbuf[3] = a0.w;
            wbuf[4] = a1.x;  wbuf[5] = a1.y;  wbuf[6] = a1.z;  wbuf[7] = a1.w;
            wbuf[8] = vx.x;  wbuf[9] = vx.y;  wbuf[10] = vx.z; wbuf[11] = vx.w;
            wbuf[12] = a3.x; wbuf[13] = a3.y; wbuf[14] = a3.z; wbuf[15] = a3.w;
            wbuf[16] = a4.x; wbuf[17] = a4.y; wbuf[18] = a4.z; wbuf[19] = a4.w;
        }
        float wo[4];
#pragma unroll
        for (int j = 0; j < 4; j++) {
            float acc = 0.f;
#pragma unroll
            for (int k = 0; k < 11; k++) acc += wbuf[j + 3 + k] * wk[k];
            wo[j] = acc * cw;
        }
        float ho[4] = {hx * chs, hy * chs, hz * chs, hw * chs};
        float xv[4] = {vx.x, vx.y, vx.z, vx.w};
        float sc[4];
#pragma unroll
        for (int j = 0; j < 4; j++) {
            float sx = 1.0f / (1.0f + expf(-xv[j]));
            sc[j] = (sx > M) ? xv[j] : 0.0f;
        }
        float s4 = sc[0] + sc[1] + sc[2] + sc[3];
        S += s4;
        Srow += (float)(r0 + y) * s4;
#pragma unroll
        for (int j = 0; j < 4; j++) {
            Sw += wo[j] * sc[j];
            Sh += ho[j] * sc[j];
            Scol += (float)(xc + j) * sc[j];
        }
        float4 o;
        o.x = sc[0]; o.y = sc[1]; o.z = sc[2]; o.w = sc[3];
        ((float4*)outS)[obase + idx] = o;
        o.x = wo[0]; o.y = wo[1]; o.z = wo[2]; o.w = wo[3];
        ((float4*)outW)[obase + idx] = o;
        o.x = ho[0]; o.y = ho[1]; o.z = ho[2]; o.w = ho[3];
        ((float4*)outH)[obase + idx] = o;
    }
    // block-reduce the 5 sums, then one atomicAdd per slot (2 halves/slot:
    // fp add of 2 partials is commutative -> bit-exact regardless of order)
#pragma unroll
    for (int off = 32; off; off >>= 1) {
        S    += __shfl_xor(S, off, 64);
        Sw   += __shfl_xor(Sw, off, 64);
        Sh   += __shfl_xor(Sh, off, 64);
        Scol += __shfl_xor(Scol, off, 64);
        Srow += __shfl_xor(Srow, off, 64);
    }
    int wid = tid >> 6, lane = tid & 63;
    if (lane == 0) {
        red[wid * 5 + 0] = S;   red[wid * 5 + 1] = Sw;
        red[wid * 5 + 2] = Sh;  red[wid * 5 + 3] = Scol;
        red[wid * 5 + 4] = Srow;
    }
    __syncthreads();
    if (tid == 0) {
        float a0 = 0, a1 = 0, a2 = 0, a3 = 0, a4 = 0;
#pragma unroll
        for (int w2 = 0; w2 < 4; w2++) {
            a0 += red[w2 * 5 + 0]; a1 += red[w2 * 5 + 1];
            a2 += red[w2 * 5 + 2]; a3 += red[w2 * 5 + 3];
            a4 += red[w2 * 5 + 4];
        }
        atomicAdd(&ws[2048 + bc], a0);   // S
        atomicAdd(&ws[3072 + bc], a1);   // Sw
        atomicAdd(&ws[4096 + bc], a2);   // Sh
        atomicAdd(&ws[5120 + bc], a3);   // Scol
        atomicAdd(&ws[6144 + bc], a4);   // Srow
    }
}

// ---------------- Kernel 3: channel-max mask, register-resident -------------
// One thread owns one (b,f,pixel) across all 64 channels. No LDS, no barriers.
__global__ __launch_bounds__(256) void k_mask(float* __restrict__ out) {
    int chunk = blockIdx.x;                 // 0..63 (256-pixel chunk)
    int f = blockIdx.y;                     // 0..2  (field)
    int b = blockIdx.z;                     // 0..15
    int tid = threadIdx.x;
    size_t base = ((size_t)b * 192 + (size_t)f * 64) * PLANE
                + (size_t)chunk * 256 + tid;
    float v[64];
#pragma unroll
    for (int c = 0; c < 64; c++) v[c] = out[base + (size_t)c * PLANE];
    float m = v[0];
#pragma unroll
    for (int c = 1; c < 64; c++) m = fmaxf(m, v[c]);
#pragma unroll
    for (int c = 0; c < 64; c++)
        out[base + (size_t)c * PLANE] = (v[c] == m) ? v[c] : 0.0f;
}

// ---------------- Kernel 4: bbox rows ----------------
__global__ __launch_bounds__(256) void k_bbox(const float* __restrict__ ws,
                                              float* __restrict__ out) {
    int idx = blockIdx.x * 256 + threadIdx.x;
    if (idx >= 1024) return;
    int b = idx >> 6;
    float S    = ws[2048 + idx];
    float Sw   = ws[3072 + idx];
    float Sh   = ws[4096 + idx];
    float Scol = ws[5120 + idx];
    float Srow = ws[6144 + idx];
    float ps   = ws[1024 + idx];
    float inv = 1.0f / S;
    float wsv = Sw * inv, hsv = Sh * inv;
    float x1 = Scol * inv - 0.5f * wsv;
    float y1 = Srow * inv - 0.5f * hsv;
    float* o = out + OUT0 + (size_t)idx * 6;
    o[0] = (float)b;
    o[1] = x1;
    o[2] = y1;
    o[3] = x1 + wsv;
    o[4] = y1 + hsv;
    o[5] = ps;
}

extern "C" void kernel_launch(void* const* d_in, const int* in_sizes, int n_in,
                              void* d_out, int out_size, void* d_ws, size_t ws_size,
                              hipStream_t stream) {
    const float* x          = (const float*)d_in[0];
    const float* w_bbx      = (const float*)d_in[1];
    const float* w_width    = (const float*)d_in[2];
    const float* w_width_sh = (const float*)d_in[3];
    const float* w_height   = (const float*)d_in[4];
    const float* w_height_sh= (const float*)d_in[5];
    float* out = (float*)d_out;
    float* ws  = (float*)d_ws;

    k_max<<<dim3(1024), dim3(256), 0, stream>>>(x, ws);
    k_fields<<<dim3(2048), dim3(256), 0, stream>>>(
        x, w_bbx, w_width, w_width_sh, w_height, w_height_sh, ws, out);
    k_mask<<<dim3(64, 3, 16), dim3(256), 0, stream>>>(out);
    k_bbox<<<dim3(4), dim3(256), 0, stream>>>(ws, out);
}